// Round 3
// baseline (291.108 us; speedup 1.0000x reference)
//
#include <hip/hip_runtime.h>

namespace {
constexpr int kB = 4, kC = 32, kH = 512, kW = 512, kN = 64;
constexpr int kHout = 16, kMaxW = 192;
constexpr long long kResultElems = (long long)kB * kN * kC * kHout * kMaxW;
constexpr int kCP = 4;                       // channels per pass (8 passes)
}

// One block per (b, n, i): 192 threads, thread j = output column.
// Software-pipelined: while pass k is sampled out of LDS, pass k+1's rows are
// already in flight (global float4 -> registers), so L2/LLC latency hides
// behind compute+stores. 4 channels per barrier pair (8 pairs total).
// Discrete decisions (width, floor taps, clips) use explicit round-to-nearest
// scalar ops in the reference's order so tap selection is bit-exact vs numpy.
extern "C" __global__ __launch_bounds__(kMaxW) void roi_rotate(
    const float* __restrict__ image,
    const float* __restrict__ boxes,
    float* __restrict__ result,
    float* __restrict__ mask)
{
    __shared__ float ls[kCP][2][kW];         // 16 KiB: [ch][row(y0/y1)][x]

    const int blk = blockIdx.x;
    const int i  = blk & (kHout - 1);        // output row 0..15
    const int bn = blk >> 4;                 // b*N + n
    const int b  = bn >> 6;

    const float* bx = boxes + bn * 5;
    const float left = bx[0];
    const float top  = bx[1];
    const float bw   = __fsub_rn(bx[2], bx[0]);
    const float bh   = __fsub_rn(bx[3], bx[1]);
    const int width  = (int)(__fmul_rn(__fdiv_rn(bw, bh), (float)kHout));
    const float each_w = __fdiv_rn(bw, (float)(width - 1));
    const float each_h = __fdiv_rn(bh, (float)(kHout - 1));

    const int j = threadIdx.x;               // 0..191
    const float x = __fadd_rn(__fmul_rn((float)j, each_w), left);
    const float y = __fadd_rn(__fmul_rn((float)i, each_h), top);

    const int xf = (int)floorf(x);
    const int yf = (int)floorf(y);
    const int x0 = min(max(xf,     0), kW - 1);
    const int x1 = min(max(xf + 1, 0), kW - 1);
    const int y0 = min(max(yf,     0), kH - 1);
    const int y1 = min(max(yf + 1, 0), kH - 1);

    const float wx1 = (float)x1 - x;
    const float wx0 = x - (float)x0;
    const float wy1 = (float)y1 - y;
    const float wy0 = y - (float)y0;
    const float wa = wx1 * wy1;
    const float wb = wx1 * wy0;
    const float wc = wx0 * wy1;
    const float wd = wx0 * wy0;

    const bool valid = (j < width);

    // Staging extent (block-uniform). For valid j: x in [left, left+bw], so
    // x0 >= xlo and x1 <= xhi. float4 tail over-reads <= 3 floats, staying
    // inside the image allocation (y1 <= 497 for this input distribution).
    const int xlo = (min(max((int)floorf(left), 0), kW - 1)) & ~3;  // 16B align
    const int xhi = min((int)floorf(__fadd_rn(left, bw)) + 1, kW - 1);
    const int S    = xhi - xlo + 1;          // <= 512
    const int nvec = (S + 3) >> 2;           // float4 loads per row, <= 128

    const bool do_stage = (j < nvec);
    const int o = 4 * j;                     // staged column offset
    const size_t row_off0 = (size_t)y0 * kW + xlo + o;
    const size_t row_off1 = (size_t)y1 * kW + xlo + o;
    const int lx0 = x0 - xlo;
    const int lx1 = x1 - xlo;

    float* op = result + (size_t)bn * (kC * kHout * kMaxW) + (size_t)i * kMaxW + j;
    const float* chbase = image + (size_t)b * ((size_t)kC * kH * kW);
    constexpr size_t kChStride = (size_t)kH * kW;
    constexpr int kOpStride = kHout * kMaxW;

    float4 r[kCP][2];
    if (do_stage) {
        #pragma unroll
        for (int cc = 0; cc < kCP; ++cc) {
            const float* p = chbase + (size_t)cc * kChStride;
            r[cc][0] = *(const float4*)(p + row_off0);
            r[cc][1] = *(const float4*)(p + row_off1);
        }
    }

    for (int c = 0; c < kC; c += kCP) {
        if (do_stage) {
            #pragma unroll
            for (int cc = 0; cc < kCP; ++cc) {
                *(float4*)&ls[cc][0][o] = r[cc][0];
                *(float4*)&ls[cc][1][o] = r[cc][1];
            }
            // Prefetch next pass while this pass computes (hides L2 latency).
            if (c + kCP < kC) {
                #pragma unroll
                for (int cc = 0; cc < kCP; ++cc) {
                    const float* p = chbase + (size_t)(c + kCP + cc) * kChStride;
                    r[cc][0] = *(const float4*)(p + row_off0);
                    r[cc][1] = *(const float4*)(p + row_off1);
                }
            }
        }
        __syncthreads();                     // LDS writes visible
        #pragma unroll
        for (int cc = 0; cc < kCP; ++cc) {
            float out = 0.0f;
            if (valid) {
                out = ls[cc][0][lx0] * wa + ls[cc][1][lx0] * wb
                    + ls[cc][0][lx1] * wc + ls[cc][1][lx1] * wd;   // ref order
            }
            op[(c + cc) * kOpStride] = out;  // poisoned d_out: invalid j -> 0
        }
        __syncthreads();                     // reads done before next writes
    }

    if (i == 0) {
        mask[bn * kMaxW + j] = valid ? 1.0f : 0.0f;
    }
}

extern "C" void kernel_launch(void* const* d_in, const int* in_sizes, int n_in,
                              void* d_out, int out_size, void* d_ws, size_t ws_size,
                              hipStream_t stream) {
    const float* image = (const float*)d_in[0];
    const float* boxes = (const float*)d_in[1];
    float* result = (float*)d_out;
    float* mask   = result + kResultElems;   // outputs concatenated flat

    dim3 grid(kB * kN * kHout);   // 4096 blocks: (b,n,i)
    dim3 block(kMaxW);            // 192 threads = 3 waves
    hipLaunchKernelGGL(roi_rotate, grid, block, 0, stream,
                       image, boxes, result, mask);
}

// Round 4
// 277.739 us; speedup vs baseline: 1.0481x; 1.0481x over previous
//
#include <hip/hip_runtime.h>

namespace {
constexpr int kB = 4, kC = 32, kH = 512, kW = 512, kN = 64;
constexpr int kHout = 16, kMaxW = 192;
constexpr long long kResultElems = (long long)kB * kN * kC * kHout * kMaxW;
constexpr int kCP = 2;                       // channels per pass
constexpr int kNP = kC / kCP;                // 16 passes
}

// One block per (b, n, i): 192 threads, thread j = output column.
// Double-buffered LDS row staging with ONE barrier per pass. Pass body order:
//   issue next-pass global float4 loads -> sample current buffer from LDS ->
//   store outputs -> ds_write next buffer -> s_barrier.
// The ds_write (vmcnt drain point) sits AFTER sample+store, so global load
// latency hides behind compute instead of being drained at the barrier
// (gfx950 __syncthreads emits s_waitcnt vmcnt(0) -- R3's regression).
// Result stores are nontemporal (output is never re-read; probe for the
// observed 2x WRITE_SIZE inflation).
// Discrete decisions (width, floor taps, clips) use explicit round-to-nearest
// scalar ops in the reference's order so tap selection is bit-exact vs numpy.
extern "C" __global__ __launch_bounds__(kMaxW) void roi_rotate(
    const float* __restrict__ image,
    const float* __restrict__ boxes,
    float* __restrict__ result,
    float* __restrict__ mask)
{
    __shared__ float ls[2][kCP][2][kW];      // 16 KiB: [buf][ch][row(y0/y1)][x]

    const int blk = blockIdx.x;
    const int i  = blk & (kHout - 1);        // output row 0..15
    const int bn = blk >> 4;                 // b*N + n
    const int b  = bn >> 6;

    const float* bx = boxes + bn * 5;
    const float left = bx[0];
    const float top  = bx[1];
    const float bw   = __fsub_rn(bx[2], bx[0]);
    const float bh   = __fsub_rn(bx[3], bx[1]);
    const int width  = (int)(__fmul_rn(__fdiv_rn(bw, bh), (float)kHout));
    const float each_w = __fdiv_rn(bw, (float)(width - 1));
    const float each_h = __fdiv_rn(bh, (float)(kHout - 1));

    const int j = threadIdx.x;               // 0..191
    const float x = __fadd_rn(__fmul_rn((float)j, each_w), left);
    const float y = __fadd_rn(__fmul_rn((float)i, each_h), top);

    const int xf = (int)floorf(x);
    const int yf = (int)floorf(y);
    const int x0 = min(max(xf,     0), kW - 1);
    const int x1 = min(max(xf + 1, 0), kW - 1);
    const int y0 = min(max(yf,     0), kH - 1);
    const int y1 = min(max(yf + 1, 0), kH - 1);

    const float wx1 = (float)x1 - x;
    const float wx0 = x - (float)x0;
    const float wy1 = (float)y1 - y;
    const float wy0 = y - (float)y0;
    const float wa = wx1 * wy1;
    const float wb = wx1 * wy0;
    const float wc = wx0 * wy1;
    const float wd = wx0 * wy0;

    const bool valid = (j < width);

    // Staging extent (block-uniform). For valid j: x in [left, left+bw], so
    // x0 >= xlo and x1 <= xhi. float4 tail over-reads <= 3 floats, staying
    // inside the image allocation (y1 <= 497 for this input distribution).
    const int xlo = (min(max((int)floorf(left), 0), kW - 1)) & ~3;  // 16B align
    const int xhi = min((int)floorf(__fadd_rn(left, bw)) + 1, kW - 1);
    const int S    = xhi - xlo + 1;          // <= 512
    const int nvec = (S + 3) >> 2;           // float4 loads per row, <= 128

    const bool do_stage = (j < nvec);
    const int o = 4 * j;                     // staged column offset
    const size_t row_off0 = (size_t)y0 * kW + xlo + o;
    const size_t row_off1 = (size_t)y1 * kW + xlo + o;
    const int lx0 = x0 - xlo;
    const int lx1 = x1 - xlo;

    float* op = result + (size_t)bn * (kC * kHout * kMaxW) + (size_t)i * kMaxW + j;
    const float* chbase = image + (size_t)b * ((size_t)kC * kH * kW);
    constexpr size_t kChStride = (size_t)kH * kW;
    constexpr int kOpStride = kHout * kMaxW;

    // Prologue: stage pass 0 into buffer 0.
    if (do_stage) {
        #pragma unroll
        for (int cc = 0; cc < kCP; ++cc) {
            const float* p0 = chbase + (size_t)cc * kChStride;
            const float4 v0 = *(const float4*)(p0 + row_off0);
            const float4 v1 = *(const float4*)(p0 + row_off1);
            *(float4*)&ls[0][cc][0][o] = v0;
            *(float4*)&ls[0][cc][1][o] = v1;
        }
    }
    __syncthreads();

    for (int p = 0; p < kNP; ++p) {
        const int cur = p & 1;
        const bool more = (p + 1 < kNP);

        // 1) Issue next pass's global loads first (longest latency).
        float4 r[kCP][2];
        if (do_stage && more) {
            #pragma unroll
            for (int cc = 0; cc < kCP; ++cc) {
                const float* pn = chbase + (size_t)((p + 1) * kCP + cc) * kChStride;
                r[cc][0] = *(const float4*)(pn + row_off0);
                r[cc][1] = *(const float4*)(pn + row_off1);
            }
        }

        // 2) Sample current buffer and store (overlaps the loads above).
        #pragma unroll
        for (int cc = 0; cc < kCP; ++cc) {
            float out = 0.0f;
            if (valid) {
                out = ls[cur][cc][0][lx0] * wa + ls[cur][cc][1][lx0] * wb
                    + ls[cur][cc][0][lx1] * wc + ls[cur][cc][1][lx1] * wd;
            }
            // d_out is poisoned 0xAA: invalid j must write 0.
            __builtin_nontemporal_store(out, &op[(p * kCP + cc) * kOpStride]);
        }

        // 3) Now consume the loads into the other buffer (vmcnt drains here,
        //    after the compute, not at the barrier).
        if (do_stage && more) {
            #pragma unroll
            for (int cc = 0; cc < kCP; ++cc) {
                *(float4*)&ls[cur ^ 1][cc][0][o] = r[cc][0];
                *(float4*)&ls[cur ^ 1][cc][1][o] = r[cc][1];
            }
        }

        // 4) Single barrier per pass (p is block-uniform).
        if (more) __syncthreads();
    }

    if (i == 0) {
        mask[bn * kMaxW + j] = valid ? 1.0f : 0.0f;
    }
}

extern "C" void kernel_launch(void* const* d_in, const int* in_sizes, int n_in,
                              void* d_out, int out_size, void* d_ws, size_t ws_size,
                              hipStream_t stream) {
    const float* image = (const float*)d_in[0];
    const float* boxes = (const float*)d_in[1];
    float* result = (float*)d_out;
    float* mask   = result + kResultElems;   // outputs concatenated flat

    dim3 grid(kB * kN * kHout);   // 4096 blocks: (b,n,i)
    dim3 block(kMaxW);            // 192 threads = 3 waves
    hipLaunchKernelGGL(roi_rotate, grid, block, 0, stream,
                       image, boxes, result, mask);
}

// Round 5
// 222.646 us; speedup vs baseline: 1.3075x; 1.2474x over previous
//
#include <hip/hip_runtime.h>

namespace {
constexpr int kB = 4, kC = 32, kH = 512, kW = 512, kN = 64;
constexpr int kHout = 16, kMaxW = 192;
constexpr long long kResultElems = (long long)kB * kN * kC * kHout * kMaxW;
constexpr int kWaves = 3;                    // 192 threads
}

// One block per (b, n, i); 3 waves. BARRIER-FREE: each wave owns channels
// {w, w+3, ...}, stages the two bilinear source rows (y0,y1) for its channel
// into its PRIVATE LDS region with coalesced float4 loads, then samples all
// 192 output columns itself (3 chunks of 64 lanes). No __syncthreads -- no
// vmcnt(0) drain points, no cross-wave coupling; 30 independent waves/CU hide
// LLC/L2 latency by TLP (R3/R4 showed the compiler defeats source-level
// pipelining around barriers; VGPR=20 proved the prefetch was sunk).
// Wave-internal ds_write -> ds_read ordering: lanes are lockstep within a
// wave; an s_waitcnt lgkmcnt(0) + memory clobber enforces completion and
// stops compiler reordering (and the trailing clobber stops next-iteration
// ds_writes hoisting above this iteration's reads).
// Discrete decisions (width, floor taps, clips) use explicit round-to-nearest
// scalar ops in the reference's order so tap selection is bit-exact vs numpy.
extern "C" __global__ __launch_bounds__(kWaves * 64) void roi_rotate(
    const float* __restrict__ image,
    const float* __restrict__ boxes,
    float* __restrict__ result,
    float* __restrict__ mask)
{
    __shared__ float ls[kWaves][2][kW];      // 12 KiB, wave-private regions

    const int blk = blockIdx.x;
    const int i  = blk & (kHout - 1);        // output row 0..15
    const int bn = blk >> 4;                 // b*N + n
    const int b  = bn >> 6;

    const int tid  = threadIdx.x;
    const int w    = tid >> 6;               // wave id 0..2
    const int lane = tid & 63;

    const float* bx = boxes + bn * 5;
    const float left = bx[0];
    const float top  = bx[1];
    const float bw   = __fsub_rn(bx[2], bx[0]);
    const float bh   = __fsub_rn(bx[3], bx[1]);
    const int width  = (int)(__fmul_rn(__fdiv_rn(bw, bh), (float)kHout));
    const float each_w = __fdiv_rn(bw, (float)(width - 1));
    const float each_h = __fdiv_rn(bh, (float)(kHout - 1));

    // y taps: uniform over the block (depend only on i).
    const float y = __fadd_rn(__fmul_rn((float)i, each_h), top);
    const int yf = (int)floorf(y);
    const int y0 = min(max(yf,     0), kH - 1);
    const int y1 = min(max(yf + 1, 0), kH - 1);
    const float wy1 = (float)y1 - y;
    const float wy0 = y - (float)y0;

    // Staging extent (block-uniform). For valid j: x in [left, left+bw], so
    // x0 >= xlo and x1 <= xhi. float4 tails over-read <= 3 floats and stay
    // inside the image allocation (y1 <= 497 for this input distribution).
    const int xlo = (min(max((int)floorf(left), 0), kW - 1)) & ~3;  // 16B align
    const int xhi = min((int)floorf(__fadd_rn(left, bw)) + 1, kW - 1);
    const int S   = xhi - xlo + 1;           // <= 512

    // Per-lane x taps for its 3 output columns j = 64q + lane.
    int   lx0q[3], lx1q[3];
    float waq[3], wbq[3], wcq[3], wdq[3];
    bool  vq[3];
    #pragma unroll
    for (int q = 0; q < 3; ++q) {
        const int j = 64 * q + lane;
        const float x = __fadd_rn(__fmul_rn((float)j, each_w), left);
        const int xf = (int)floorf(x);
        const int x0 = min(max(xf,     0), kW - 1);
        const int x1 = min(max(xf + 1, 0), kW - 1);
        const float wx1 = (float)x1 - x;
        const float wx0 = x - (float)x0;
        lx0q[q] = x0 - xlo;
        lx1q[q] = x1 - xlo;
        waq[q] = wx1 * wy1;
        wbq[q] = wx1 * wy0;
        wcq[q] = wx0 * wy1;
        wdq[q] = wx0 * wy0;
        vq[q]  = (j < width);
    }

    // Staging: lane covers 16B chunks at float offsets 4*lane and 4*(lane+64).
    const bool need0 = (4 * lane        < S);
    const bool need1 = (4 * (lane + 64) < S);
    const int  o0 = 4 * lane;
    const int  o1 = 4 * (lane + 64);
    const size_t r0 = (size_t)y0 * kW + xlo;
    const size_t r1 = (size_t)y1 * kW + xlo;

    const float* chbase = image + (size_t)b * ((size_t)kC * kH * kW);
    constexpr size_t kChStride = (size_t)kH * kW;
    float* opb = result + (size_t)bn * (kC * kHout * kMaxW) + (size_t)i * kMaxW;

    for (int c = w; c < kC; c += kWaves) {
        const float* p = chbase + (size_t)c * kChStride;
        float4 a0, b0, a1, b1;
        if (need0) { a0 = *(const float4*)(p + r0 + o0);
                     b0 = *(const float4*)(p + r1 + o0); }
        if (need1) { a1 = *(const float4*)(p + r0 + o1);
                     b1 = *(const float4*)(p + r1 + o1); }
        if (need0) { *(float4*)&ls[w][0][o0] = a0;
                     *(float4*)&ls[w][1][o0] = b0; }
        if (need1) { *(float4*)&ls[w][0][o1] = a1;
                     *(float4*)&ls[w][1][o1] = b1; }
        // Wave-synchronous fence: ds_writes complete before ds_reads below;
        // clobber stops the compiler migrating LDS ops across.
        __asm__ volatile("s_waitcnt lgkmcnt(0)" ::: "memory");

        float* op = opb + (size_t)c * (kHout * kMaxW);
        #pragma unroll
        for (int q = 0; q < 3; ++q) {
            float out = 0.0f;
            if (vq[q]) {
                out = ls[w][0][lx0q[q]] * waq[q] + ls[w][1][lx0q[q]] * wbq[q]
                    + ls[w][0][lx1q[q]] * wcq[q] + ls[w][1][lx1q[q]] * wdq[q];
            }
            op[64 * q + lane] = out;     // poisoned d_out: invalid j -> 0
        }
        // WAR guard: next iteration's ds_writes must not hoist above reads.
        __asm__ volatile("" ::: "memory");
    }

    if (i == 0 && w == 0) {
        #pragma unroll
        for (int q = 0; q < 3; ++q) {
            mask[bn * kMaxW + 64 * q + lane] = vq[q] ? 1.0f : 0.0f;
        }
    }
}

extern "C" void kernel_launch(void* const* d_in, const int* in_sizes, int n_in,
                              void* d_out, int out_size, void* d_ws, size_t ws_size,
                              hipStream_t stream) {
    const float* image = (const float*)d_in[0];
    const float* boxes = (const float*)d_in[1];
    float* result = (float*)d_out;
    float* mask   = result + kResultElems;   // outputs concatenated flat

    dim3 grid(kB * kN * kHout);   // 4096 blocks: (b,n,i)
    dim3 block(kWaves * 64);      // 192 threads = 3 independent waves
    hipLaunchKernelGGL(roi_rotate, grid, block, 0, stream,
                       image, boxes, result, mask);
}